// Round 2
// baseline (4142.673 us; speedup 1.0000x reference)
//
#include <hip/hip_runtime.h>
#include <math.h>

#define Hdim 384
#define Wdim 384
#define HW (Hdim * Wdim)          // 147456
#define Bn 8
#define NB4 (HW / 1024)           // 144 blocks per image (256 thr x 4 px)
#define MAXITER 50
#define TOLF 1e-6f
#define EPSF 1e-12f

// ---------- helpers ----------

__device__ __forceinline__ int symidx(int t, int n) {
    if (t < 0) t = -t - 1;
    else if (t >= n) t = 2 * n - 1 - t;
    return t;
}

__device__ __forceinline__ float blockReduceSum(float v) {
    __shared__ float sm[256];
    sm[threadIdx.x] = v;
    __syncthreads();
    for (int s = 128; s > 0; s >>= 1) {
        if (threadIdx.x < s) sm[threadIdx.x] += sm[threadIdx.x + s];
        __syncthreads();
    }
    float r = sm[0];
    __syncthreads();
    return r;
}

__device__ __forceinline__ void blockReduce2(float& a, float& b) {
    __shared__ float sa[256], sb[256];
    sa[threadIdx.x] = a; sb[threadIdx.x] = b;
    __syncthreads();
    for (int s = 128; s > 0; s >>= 1) {
        if (threadIdx.x < s) {
            sa[threadIdx.x] += sa[threadIdx.x + s];
            sb[threadIdx.x] += sb[threadIdx.x + s];
        }
        __syncthreads();
    }
    a = sa[0]; b = sb[0];
    __syncthreads();
}

// scalar (boundary) sym_conv: out[i,j] = sum_{u,v} k[u,v] * g[sym(i+2-u), sym(j+2-v)]
__device__ float symconv_s(const float* __restrict__ g, const float* kr, int i, int j) {
    float acc = 0.f;
#pragma unroll
    for (int u = 0; u < 5; ++u) {
        int rr = symidx(i + 2 - u, Hdim);
        const float* row = g + rr * Wdim;
#pragma unroll
        for (int v = 0; v < 5; ++v) {
            int cc = symidx(j + 2 - v, Wdim);
            acc += kr[u * 5 + v] * row[cc];
        }
    }
    return acc;
}

// scalar (boundary) sym_conv_T with symmetric-pad adjoint
__device__ float symconvT_s(const float* __restrict__ g, const float* kr, int m, int n) {
    int pr[2]; int nr = 0;
    pr[nr++] = m + 2;
    if (m < 2)         pr[nr++] = 1 - m;
    if (m >= Hdim - 2) pr[nr++] = 2 * Hdim + 1 - m;
    int pc[2]; int nc = 0;
    pc[nc++] = n + 2;
    if (n < 2)         pc[nc++] = 1 - n;
    if (n >= Wdim - 2) pc[nc++] = 2 * Wdim + 1 - n;

    float acc = 0.f;
    for (int a = 0; a < nr; ++a) {
        int p = pr[a];
        for (int bb = 0; bb < nc; ++bb) {
            int q = pc[bb];
#pragma unroll
            for (int u = 0; u < 5; ++u) {
                int rr = p + u - 4;
                if ((unsigned)rr < (unsigned)Hdim) {
                    const float* row = g + rr * Wdim;
#pragma unroll
                    for (int v = 0; v < 5; ++v) {
                        int cc = q + v - 4;
                        if ((unsigned)cc < (unsigned)Wdim)
                            acc += kr[u * 5 + v] * row[cc];
                    }
                }
            }
        }
    }
    return acc;
}

// ---------- kernels ----------

// rden = 1 / max(sum_c |f_c|, EPS)   (4 px / thread)
__global__ __launch_bounds__(256) void k_prep(const float* __restrict__ f, float* __restrict__ rden) {
    int b = blockIdx.y;
    int p4 = (blockIdx.x * 256 + threadIdx.x) << 2;
    float s0 = 0, s1 = 0, s2 = 0, s3 = 0;
#pragma unroll
    for (int c = 0; c < 9; ++c) {
        float4 fv = *(const float4*)(f + ((size_t)(b * 9 + c)) * HW + p4);
        s0 += fabsf(fv.x); s1 += fabsf(fv.y); s2 += fabsf(fv.z); s3 += fabsf(fv.w);
    }
    float4 o;
    o.x = 1.f / fmaxf(s0, EPSF); o.y = 1.f / fmaxf(s1, EPSF);
    o.z = 1.f / fmaxf(s2, EPSF); o.w = 1.f / fmaxf(s3, EPSF);
    *(float4*)(rden + (size_t)b * HW + p4) = o;
}

// b = K^T y ; r = d = b ; x = 0 ; partials of b*b -> rrpart
__global__ __launch_bounds__(256) void k_init(const float* __restrict__ y, const float* __restrict__ kk,
                                              float* __restrict__ r, float* __restrict__ d,
                                              float* __restrict__ x, float* __restrict__ part) {
    int b = blockIdx.y;
    int p4 = (blockIdx.x * 256 + threadIdx.x) << 2;
    int m = p4 / Wdim, n = p4 - m * Wdim;
    float kr[25];
#pragma unroll
    for (int t = 0; t < 25; ++t) kr[t] = kk[b * 25 + t];
    const float* gb = y + (size_t)b * HW;
    float a0, a1, a2, a3;
    if (m >= 2 && m <= Hdim - 3 && n >= 4 && n <= Wdim - 8) {
        a0 = a1 = a2 = a3 = 0.f;
#pragma unroll
        for (int u = 0; u < 5; ++u) {
            const float* row = gb + (m + u - 2) * Wdim + n - 2;
            float w[8];
#pragma unroll
            for (int z = 0; z < 8; ++z) w[z] = row[z];
#pragma unroll
            for (int v = 0; v < 5; ++v) {
                float kv = kr[u * 5 + v];
                a0 += kv * w[v]; a1 += kv * w[v + 1]; a2 += kv * w[v + 2]; a3 += kv * w[v + 3];
            }
        }
    } else {
        a0 = symconvT_s(gb, kr, m, n);
        a1 = symconvT_s(gb, kr, m, n + 1);
        a2 = symconvT_s(gb, kr, m, n + 2);
        a3 = symconvT_s(gb, kr, m, n + 3);
    }
    size_t off = (size_t)b * HW + p4;
    float4 v = make_float4(a0, a1, a2, a3);
    *(float4*)(r + off) = v;
    *(float4*)(d + off) = v;
    *(float4*)(x + off) = make_float4(0.f, 0.f, 0.f, 0.f);
    float ps = blockReduceSum(a0 * a0 + a1 * a1 + a2 * a2 + a3 * a3);
    if (threadIdx.x == 0) part[b * NB4 + blockIdx.x] = ps;
}

// thr, conv0 from init partials
__global__ __launch_bounds__(256) void k_init2(const float* __restrict__ part, float* __restrict__ thr,
                                               int* __restrict__ conv) {
    int b = blockIdx.x;
    float s = (threadIdx.x < NB4) ? part[b * NB4 + threadIdx.x] : 0.f;
    s = blockReduceSum(s);
    if (threadIdx.x == 0) {
        thr[b] = TOLF * s;
        conv[b] = (s <= TOLF * s) ? 1 : 0;
    }
}

// t1 = sym_conv(d) ; u2 = rden^2 * (sum_c f_c * d[.+delta_c])
__global__ __launch_bounds__(256) void k_A(const float* __restrict__ dvec, const float* __restrict__ f,
                                           const float* __restrict__ rden, const float* __restrict__ kk,
                                           float* __restrict__ t1, float* __restrict__ u2) {
    int b = blockIdx.y;
    int p4 = (blockIdx.x * 256 + threadIdx.x) << 2;
    int i = p4 / Wdim, j = p4 - i * Wdim;
    float kr[25];
#pragma unroll
    for (int t = 0; t < 25; ++t) kr[t] = kk[b * 25 + t];
    const float* db = dvec + (size_t)b * HW;

    // --- t1 ---
    float a0, a1, a2, a3;
    if (i >= 2 && i <= Hdim - 3 && j >= 4 && j <= Wdim - 8) {
        a0 = a1 = a2 = a3 = 0.f;
#pragma unroll
        for (int u = 0; u < 5; ++u) {
            const float* row = db + (i + 2 - u) * Wdim + j - 2;
            float w[8];
#pragma unroll
            for (int z = 0; z < 8; ++z) w[z] = row[z];
#pragma unroll
            for (int v = 0; v < 5; ++v) {
                float kv = kr[u * 5 + v];
                a0 += kv * w[4 - v]; a1 += kv * w[5 - v]; a2 += kv * w[6 - v]; a3 += kv * w[7 - v];
            }
        }
    } else {
        a0 = symconv_s(db, kr, i, j);
        a1 = symconv_s(db, kr, i, j + 1);
        a2 = symconv_s(db, kr, i, j + 2);
        a3 = symconv_s(db, kr, i, j + 3);
    }

    // --- raw spatial conv ---
    float s0 = 0, s1 = 0, s2 = 0, s3 = 0;
    if (i >= 1 && i <= Hdim - 2 && j >= 4 && j <= Wdim - 8) {
#pragma unroll
        for (int c = 0; c < 9; ++c) {
            float4 fc = *(const float4*)(f + ((size_t)(b * 9 + c)) * HW + p4);
            const float* rowd = db + (i + c / 3 - 1) * Wdim + j + (c % 3) - 1;
            s0 += fc.x * rowd[0]; s1 += fc.y * rowd[1]; s2 += fc.z * rowd[2]; s3 += fc.w * rowd[3];
        }
    } else {
#pragma unroll
        for (int c = 0; c < 9; ++c) {
            float4 fc = *(const float4*)(f + ((size_t)(b * 9 + c)) * HW + p4);
            int di = c / 3 - 1, dj = c % 3 - 1;
            int rr = i + di;
            if ((unsigned)rr < (unsigned)Hdim) {
                const float* rowd = db + rr * Wdim;
                int c0 = j + dj;
                if ((unsigned)c0 < (unsigned)Wdim) s0 += fc.x * rowd[c0];
                if ((unsigned)(c0 + 1) < (unsigned)Wdim) s1 += fc.y * rowd[c0 + 1];
                if ((unsigned)(c0 + 2) < (unsigned)Wdim) s2 += fc.z * rowd[c0 + 2];
                if ((unsigned)(c0 + 3) < (unsigned)Wdim) s3 += fc.w * rowd[c0 + 3];
            }
        }
    }
    size_t off = (size_t)b * HW + p4;
    float4 rd = *(const float4*)(rden + off);
    *(float4*)(t1 + off) = make_float4(a0, a1, a2, a3);
    *(float4*)(u2 + off) = make_float4(rd.x * rd.x * s0, rd.y * rd.y * s1,
                                       rd.z * rd.z * s2, rd.w * rd.w * s3);
}

// q = sym_conv_T(t1) + lam * sum_c f[c, .-delta_c] * u2[.-delta_c] ; partials d.q
__global__ __launch_bounds__(256) void k_B(const float* __restrict__ t1, const float* __restrict__ u2,
                                           const float* __restrict__ f, const float* __restrict__ kk,
                                           const float* __restrict__ rw, const float* __restrict__ dvec,
                                           float* __restrict__ q, float* __restrict__ part) {
    int b = blockIdx.y;
    int p4 = (blockIdx.x * 256 + threadIdx.x) << 2;
    int m = p4 / Wdim, n = p4 - m * Wdim;
    float kr[25];
#pragma unroll
    for (int t = 0; t < 25; ++t) kr[t] = kk[b * 25 + t];
    size_t bHW = (size_t)b * HW;
    const float* t1b = t1 + bHW;
    const float* u2b = u2 + bHW;

    // --- sym_conv_T(t1) ---
    float a0, a1, a2, a3;
    if (m >= 2 && m <= Hdim - 3 && n >= 4 && n <= Wdim - 8) {
        a0 = a1 = a2 = a3 = 0.f;
#pragma unroll
        for (int u = 0; u < 5; ++u) {
            const float* row = t1b + (m + u - 2) * Wdim + n - 2;
            float w[8];
#pragma unroll
            for (int z = 0; z < 8; ++z) w[z] = row[z];
#pragma unroll
            for (int v = 0; v < 5; ++v) {
                float kv = kr[u * 5 + v];
                a0 += kv * w[v]; a1 += kv * w[v + 1]; a2 += kv * w[v + 2]; a3 += kv * w[v + 3];
            }
        }
    } else {
        a0 = symconvT_s(t1b, kr, m, n);
        a1 = symconvT_s(t1b, kr, m, n + 1);
        a2 = symconvT_s(t1b, kr, m, n + 2);
        a3 = symconvT_s(t1b, kr, m, n + 3);
    }

    // --- adjoint KPN gather ---
    float s0 = 0, s1 = 0, s2 = 0, s3 = 0;
    if (m >= 1 && m <= Hdim - 2 && n >= 4 && n <= Wdim - 8) {
#pragma unroll
        for (int c = 0; c < 9; ++c) {
            int pp = (m - (c / 3 - 1)) * Wdim + n - (c % 3 - 1);
            const float* fr = f + ((size_t)(b * 9 + c)) * HW + pp;
            const float* ur = u2b + pp;
            s0 += fr[0] * ur[0]; s1 += fr[1] * ur[1]; s2 += fr[2] * ur[2]; s3 += fr[3] * ur[3];
        }
    } else {
#pragma unroll
        for (int c = 0; c < 9; ++c) {
            int di = c / 3 - 1, dj = c % 3 - 1;
            int rr = m - di;
            if ((unsigned)rr < (unsigned)Hdim) {
                const float* fr = f + ((size_t)(b * 9 + c)) * HW + rr * Wdim;
                const float* ur = u2b + rr * Wdim;
                int c0 = n - dj;
                if ((unsigned)c0 < (unsigned)Wdim) s0 += fr[c0] * ur[c0];
                if ((unsigned)(c0 + 1) < (unsigned)Wdim) s1 += fr[c0 + 1] * ur[c0 + 1];
                if ((unsigned)(c0 + 2) < (unsigned)Wdim) s2 += fr[c0 + 2] * ur[c0 + 2];
                if ((unsigned)(c0 + 3) < (unsigned)Wdim) s3 += fr[c0 + 3] * ur[c0 + 3];
            }
        }
    }
    float lam = expf(rw[0]);
    float q0 = a0 + lam * s0, q1 = a1 + lam * s1, q2 = a2 + lam * s2, q3 = a3 + lam * s3;
    *(float4*)(q + bHW + p4) = make_float4(q0, q1, q2, q3);
    float4 dv4 = *(const float4*)(dvec + bHW + p4);
    float ps = blockReduceSum(dv4.x * q0 + dv4.y * q1 + dv4.z * q2 + dv4.w * q3);
    if (threadIdx.x == 0) part[b * NB4 + blockIdx.x] = ps;
}

// alpha (from partials) ; x += a d ; r -= a q ; partials r.r
__global__ __launch_bounds__(256) void k_C(const float* __restrict__ dqpart, const float* __restrict__ rrOld,
                                           const int* __restrict__ convR, const float* __restrict__ dvec,
                                           const float* __restrict__ q, float* __restrict__ x,
                                           float* __restrict__ r, float* __restrict__ rrNew) {
    int b = blockIdx.y;
    float dq = (threadIdx.x < NB4) ? dqpart[b * NB4 + threadIdx.x] : 0.f;
    float ro = (threadIdx.x < NB4) ? rrOld[b * NB4 + threadIdx.x] : 0.f;
    blockReduce2(dq, ro);                 // dq = d.q, ro = delta_old
    float a = convR[b] ? 0.f : ro / dq;

    size_t off = (size_t)b * HW + ((size_t)blockIdx.x * 256 + threadIdx.x) * 4;
    float4 xv = *(const float4*)(x + off);
    float4 dv = *(const float4*)(dvec + off);
    float4 qv = *(const float4*)(q + off);
    float4 rv = *(const float4*)(r + off);
    xv.x += a * dv.x; xv.y += a * dv.y; xv.z += a * dv.z; xv.w += a * dv.w;
    rv.x -= a * qv.x; rv.y -= a * qv.y; rv.z -= a * qv.z; rv.w -= a * qv.w;
    *(float4*)(x + off) = xv;
    *(float4*)(r + off) = rv;
    float ps = blockReduceSum(rv.x * rv.x + rv.y * rv.y + rv.z * rv.z + rv.w * rv.w);
    if (threadIdx.x == 0) rrNew[b * NB4 + blockIdx.x] = ps;
}

// beta (from partials) ; d = r + beta d ; conv update (ping-pong)
__global__ __launch_bounds__(256) void k_D(const float* __restrict__ rrNew, const float* __restrict__ rrOld,
                                           const int* __restrict__ convR, const float* __restrict__ thr,
                                           const float* __restrict__ r, float* __restrict__ dvec,
                                           int* __restrict__ convW) {
    int b = blockIdx.y;
    float dn = (threadIdx.x < NB4) ? rrNew[b * NB4 + threadIdx.x] : 0.f;
    float dold = (threadIdx.x < NB4) ? rrOld[b * NB4 + threadIdx.x] : 0.f;
    blockReduce2(dn, dold);
    float beta = dn / dold;

    size_t off = (size_t)b * HW + ((size_t)blockIdx.x * 256 + threadIdx.x) * 4;
    float4 rv = *(const float4*)(r + off);
    float4 dv = *(const float4*)(dvec + off);
    dv.x = rv.x + beta * dv.x; dv.y = rv.y + beta * dv.y;
    dv.z = rv.z + beta * dv.z; dv.w = rv.w + beta * dv.w;
    *(float4*)(dvec + off) = dv;
    if (blockIdx.x == 0 && threadIdx.x == 0)
        convW[b] = (convR[b] || dn <= thr[b]) ? 1 : 0;
}

// ---------- launch ----------

extern "C" void kernel_launch(void* const* d_in, const int* in_sizes, int n_in,
                              void* d_out, int out_size, void* d_ws, size_t ws_size,
                              hipStream_t stream) {
    const float* y  = (const float*)d_in[0];   // [8,1,384,384]
    const float* kk = (const float*)d_in[1];   // [8,5,5]
    const float* f  = (const float*)d_in[2];   // [8,9,384,384]
    const float* rw = (const float*)d_in[3];   // [1]

    float* x = (float*)d_out;
    float* ws = (float*)d_ws;
    const size_t N = (size_t)Bn * HW;

    float* rden   = ws;
    float* r      = ws + 1 * N;
    float* dv     = ws + 2 * N;
    float* q      = ws + 3 * N;
    float* t1     = ws + 4 * N;
    float* u2     = ws + 5 * N;
    float* dqpart = ws + 6 * N;                    // Bn*NB4
    float* rrp0   = dqpart + (size_t)Bn * NB4;     // Bn*NB4
    float* rrp1   = rrp0 + (size_t)Bn * NB4;       // Bn*NB4
    float* thr    = rrp1 + (size_t)Bn * NB4;       // Bn
    int*   conv0  = (int*)(thr + Bn);              // Bn
    int*   conv1  = conv0 + Bn;                    // Bn
    float* rrp[2] = { rrp0, rrp1 };
    int*   cv[2]  = { conv0, conv1 };

    dim3 gridP(NB4, Bn), blk(256);

    k_prep<<<gridP, blk, 0, stream>>>(f, rden);
    k_init<<<gridP, blk, 0, stream>>>(y, kk, r, dv, x, rrp1);
    k_init2<<<dim3(Bn), blk, 0, stream>>>(rrp1, thr, conv1);

    for (int t = 0; t < MAXITER; ++t) {
        int np = t & 1, op = np ^ 1;
        k_A<<<gridP, blk, 0, stream>>>(dv, f, rden, kk, t1, u2);
        k_B<<<gridP, blk, 0, stream>>>(t1, u2, f, kk, rw, dv, q, dqpart);
        k_C<<<gridP, blk, 0, stream>>>(dqpart, rrp[op], cv[op], dv, q, x, r, rrp[np]);
        k_D<<<gridP, blk, 0, stream>>>(rrp[np], rrp[op], cv[op], thr, r, dv, cv[np]);
    }
}

// Round 3
// 3261.740 us; speedup vs baseline: 1.2701x; 1.2701x over previous
//
#include <hip/hip_runtime.h>
#include <math.h>

#define Hdim 384
#define Wdim 384
#define HW (Hdim * Wdim)          // 147456
#define Bn 8
#define MAXITER 50
#define TOLF 1e-6f
#define EPSF 1e-12f

// K1 tiling: 32 wide x 16 tall, 128 threads, 4 px/thread
#define TH 16
#define TW 32
#define NTX 12                    // 384/32 tile cols
#define NTB 288                   // tiles per image (12 x 24)
#define DSH 28                    // TH+12 (halo 6)
#define DSW 44                    // TW+12
#define DSP 45                    // padded stride
#define T1H 24                    // TH+8 (halo 4)
#define T1W 40
#define T1P 41
#define U2H 18                    // TH+2 (halo 1)
#define U2W 34
#define U2P 35

// ---------- helpers ----------

__device__ __forceinline__ int symidx(int t, int n) {
    if (t < 0) t = -t - 1;
    else if (t >= n) t = 2 * n - 1 - t;
    return t;
}

__device__ __forceinline__ float blockReduceSum256(float v) {
    __shared__ float sm[256];
    sm[threadIdx.x] = v;
    __syncthreads();
    for (int s = 128; s > 0; s >>= 1) {
        if (threadIdx.x < s) sm[threadIdx.x] += sm[threadIdx.x + s];
        __syncthreads();
    }
    float r = sm[0];
    __syncthreads();
    return r;
}

// global-memory sym_conv_T (used only in k_init; proven in rounds 1-2)
__device__ float symconvT_s(const float* __restrict__ g, const float* kr, int m, int n) {
    int pr[2]; int nr = 0;
    pr[nr++] = m + 2;
    if (m < 2)         pr[nr++] = 1 - m;
    if (m >= Hdim - 2) pr[nr++] = 2 * Hdim + 1 - m;
    int pc[2]; int nc = 0;
    pc[nc++] = n + 2;
    if (n < 2)         pc[nc++] = 1 - n;
    if (n >= Wdim - 2) pc[nc++] = 2 * Wdim + 1 - n;

    float acc = 0.f;
    for (int a = 0; a < nr; ++a) {
        int p = pr[a];
        for (int bb = 0; bb < nc; ++bb) {
            int q = pc[bb];
#pragma unroll
            for (int u = 0; u < 5; ++u) {
                int rr = p + u - 4;
                if ((unsigned)rr < (unsigned)Hdim) {
                    const float* row = g + rr * Wdim;
#pragma unroll
                    for (int v = 0; v < 5; ++v) {
                        int cc = q + v - 4;
                        if ((unsigned)cc < (unsigned)Wdim)
                            acc += kr[u * 5 + v] * row[cc];
                    }
                }
            }
        }
    }
    return acc;
}

// ---------- small kernels ----------

// rden = 1 / max(sum_c |f_c|, EPS)
__global__ __launch_bounds__(256) void k_prep(const float* __restrict__ f, float* __restrict__ rden) {
    int b = blockIdx.y;
    int p4 = (blockIdx.x * 256 + threadIdx.x) << 2;
    float s0 = 0, s1 = 0, s2 = 0, s3 = 0;
#pragma unroll
    for (int c = 0; c < 9; ++c) {
        float4 fv = *(const float4*)(f + ((size_t)(b * 9 + c)) * HW + p4);
        s0 += fabsf(fv.x); s1 += fabsf(fv.y); s2 += fabsf(fv.z); s3 += fabsf(fv.w);
    }
    float4 o;
    o.x = 1.f / fmaxf(s0, EPSF); o.y = 1.f / fmaxf(s1, EPSF);
    o.z = 1.f / fmaxf(s2, EPSF); o.w = 1.f / fmaxf(s3, EPSF);
    *(float4*)(rden + (size_t)b * HW + p4) = o;
}

// r = b = K^T y ; x = 0 ; partials of b*b
__global__ __launch_bounds__(256) void k_init(const float* __restrict__ y, const float* __restrict__ kk,
                                              float* __restrict__ r, float* __restrict__ x,
                                              float* __restrict__ part) {
    __shared__ float krs[25];
    int b = blockIdx.y;
    if (threadIdx.x < 25) krs[threadIdx.x] = kk[b * 25 + threadIdx.x];
    __syncthreads();
    int p2 = (blockIdx.x * 256 + threadIdx.x) * 2;
    int m = p2 / Wdim, n = p2 - m * Wdim;
    const float* gb = y + (size_t)b * HW;
    float a0 = symconvT_s(gb, krs, m, n);
    float a1 = symconvT_s(gb, krs, m, n + 1);
    size_t off = (size_t)b * HW + p2;
    r[off] = a0; r[off + 1] = a1;
    x[off] = 0.f; x[off + 1] = 0.f;
    float ps = blockReduceSum256(a0 * a0 + a1 * a1);
    if (threadIdx.x == 0) part[b * NTB + blockIdx.x] = ps;
}

// ---------- K1: fused beta/d-update + A-apply (q = K^TK d + lam L^TL d) ----------

__global__ __launch_bounds__(128) void K1(
    const float* __restrict__ r, const float* __restrict__ dold,
    float* __restrict__ dnew, float* __restrict__ q,
    const float* __restrict__ f, const float* __restrict__ rden,
    const float* __restrict__ kk, const float* __restrict__ rw,
    const float* __restrict__ rrp, float* __restrict__ dqp,
    const float* __restrict__ deltaOld, float* __restrict__ deltaNew,
    const int* __restrict__ convOld, int* __restrict__ convNew,
    float* __restrict__ thrS, int isFirst)
{
    __shared__ float ds[DSH][DSP];
    __shared__ float t1s[T1H][T1P];
    __shared__ float u2s[U2H][U2P];
    __shared__ float krs[25];
    __shared__ float red[128];

    int b = blockIdx.y;
    int bx = blockIdx.x;
    int ty = bx / NTX, tx = bx - ty * NTX;
    int r0 = ty * TH, c0 = tx * TW;
    int tid = threadIdx.x;
    size_t bHW = (size_t)b * HW;
    const float* rb = r + bHW;
    const float* db = dold + bHW;
    const float* fb = f + (size_t)b * 9 * HW;

    if (tid < 25) krs[tid] = kk[b * 25 + tid];

    // ---- phase 1: delta_t = sum(rr partials); beta ----
    float s = 0.f;
    for (int e = tid; e < NTB; e += 128) s += rrp[b * NTB + e];
    red[tid] = s; __syncthreads();
    for (int st = 64; st > 0; st >>= 1) {
        if (tid < st) red[tid] += red[tid + st];
        __syncthreads();
    }
    float delta = red[0];
    __syncthreads();
    float beta = isFirst ? 0.f : delta / deltaOld[b];
    if (bx == 0 && tid == 0) {
        deltaNew[b] = delta;
        if (isFirst) {
            float th = TOLF * delta;
            thrS[b] = th;
            convNew[b] = (delta <= th) ? 1 : 0;
        } else {
            convNew[b] = (convOld[b] || delta <= thrS[b]) ? 1 : 0;
        }
    }

    // ---- phase 2: d_s = r + beta*d_old (tile + halo 6; OOB -> 0) ----
    for (int e = tid; e < DSH * DSW; e += 128) {
        int lr = e / DSW, lc = e - lr * DSW;
        int gr = r0 - 6 + lr, gc = c0 - 6 + lc;
        float v = 0.f;
        if ((unsigned)gr < (unsigned)Hdim && (unsigned)gc < (unsigned)Wdim) {
            size_t gg = (size_t)gr * Wdim + gc;
            v = rb[gg];
            if (!isFirst) v += beta * db[gg];
        }
        ds[lr][lc] = v;
    }
    __syncthreads();

    int trr = tid >> 3;               // 0..15
    int tcc = (tid & 7) << 2;         // 0,4,...,28
    // write own tile of d_new
    {
        float4 dv = make_float4(ds[trr + 6][tcc + 6], ds[trr + 6][tcc + 7],
                                ds[trr + 6][tcc + 8], ds[trr + 6][tcc + 9]);
        *(float4*)(dnew + bHW + (size_t)(r0 + trr) * Wdim + c0 + tcc) = dv;
    }

    bool interior = (r0 >= 16 && r0 <= 352 && c0 >= 32 && c0 <= 320);

    // ---- phase 3: u2 = rden^2 * sum_c f[c,pp]*d[pp+delta_c]  (tile + halo 1) ----
    for (int e = tid; e < U2H * U2W; e += 128) {
        int a = e / U2W, ee = e - a * U2W;
        int gr = r0 - 1 + a, gc = c0 - 1 + ee;
        float v = 0.f;
        if ((unsigned)gr < (unsigned)Hdim && (unsigned)gc < (unsigned)Wdim) {
            size_t gg = (size_t)gr * Wdim + gc;
            float acc = 0.f;
#pragma unroll
            for (int c = 0; c < 9; ++c) {
                int di = c / 3 - 1, dj = c % 3 - 1;
                acc += fb[(size_t)c * HW + gg] * ds[a + di + 5][ee + dj + 5];
            }
            float rd = rden[bHW + gg];
            v = rd * rd * acc;
        }
        u2s[a][ee] = v;
    }

    // ---- phase 4: t1 = sym_conv(d)  (tile + halo 4) ----
    if (interior) {
        for (int e = tid; e < 240; e += 128) {
            int lr = e / 10, lc4 = (e - lr * 10) * 4;
            float a0 = 0, a1 = 0, a2 = 0, a3 = 0;
#pragma unroll
            for (int u = 0; u < 5; ++u) {
                const float* drow = &ds[lr + 4 - u][lc4];
                float w[8];
#pragma unroll
                for (int z = 0; z < 8; ++z) w[z] = drow[z];
#pragma unroll
                for (int v = 0; v < 5; ++v) {
                    float kv = krs[u * 5 + v];
                    a0 += kv * w[4 - v]; a1 += kv * w[5 - v];
                    a2 += kv * w[6 - v]; a3 += kv * w[7 - v];
                }
            }
            t1s[lr][lc4] = a0; t1s[lr][lc4 + 1] = a1;
            t1s[lr][lc4 + 2] = a2; t1s[lr][lc4 + 3] = a3;
        }
    } else {
        for (int e = tid; e < T1H * T1W; e += 128) {
            int lr = e / T1W, lc = e - lr * T1W;
            int gi = r0 - 4 + lr, gj = c0 - 4 + lc;
            float v = 0.f;
            if ((unsigned)gi < (unsigned)Hdim && (unsigned)gj < (unsigned)Wdim) {
                float acc = 0.f;
#pragma unroll
                for (int u = 0; u < 5; ++u) {
                    int rr = symidx(gi + 2 - u, Hdim) - (r0 - 6);
#pragma unroll
                    for (int vv = 0; vv < 5; ++vv) {
                        int cc = symidx(gj + 2 - vv, Wdim) - (c0 - 6);
                        acc += krs[u * 5 + vv] * ds[rr][cc];
                    }
                }
                v = acc;
            }
            t1s[lr][lc] = v;
        }
    }
    __syncthreads();

    // ---- phase 5: q = sym_conv_T(t1) + lam * gather(f*u2) ; dq partials ----
    float lam = expf(rw[0]);
    int m = r0 + trr, n = c0 + tcc;
    float q0, q1, q2, q3;
    if (interior) {
        float a0 = 0, a1 = 0, a2 = 0, a3 = 0;
#pragma unroll
        for (int u = 0; u < 5; ++u) {
            const float* t1row = &t1s[trr + 2 + u][tcc + 2];
            float w[8];
#pragma unroll
            for (int z = 0; z < 8; ++z) w[z] = t1row[z];
#pragma unroll
            for (int v = 0; v < 5; ++v) {
                float kv = krs[u * 5 + v];
                a0 += kv * w[v]; a1 += kv * w[v + 1];
                a2 += kv * w[v + 2]; a3 += kv * w[v + 3];
            }
        }
        float s0 = 0, s1 = 0, s2 = 0, s3 = 0;
#pragma unroll
        for (int c = 0; c < 9; ++c) {
            int di = c / 3 - 1, dj = c % 3 - 1;
            int rr = m - di, cc = n - dj;
            const float* fr = fb + (size_t)c * HW + (size_t)rr * Wdim + cc;
            const float* ur = &u2s[trr - di + 1][tcc - dj + 1];
            s0 += fr[0] * ur[0]; s1 += fr[1] * ur[1];
            s2 += fr[2] * ur[2]; s3 += fr[3] * ur[3];
        }
        q0 = a0 + lam * s0; q1 = a1 + lam * s1;
        q2 = a2 + lam * s2; q3 = a3 + lam * s3;
    } else {
        float qo[4];
#pragma unroll
        for (int o = 0; o < 4; ++o) {
            int nn = n + o;
            // sym_conv_T via LDS t1s (pad-adjoint sets; all targets in-halo)
            int pr[2]; int nr = 0;
            pr[nr++] = m + 2;
            if (m < 2)         pr[nr++] = 1 - m;
            if (m >= Hdim - 2) pr[nr++] = 2 * Hdim + 1 - m;
            int pc[2]; int nc = 0;
            pc[nc++] = nn + 2;
            if (nn < 2)         pc[nc++] = 1 - nn;
            if (nn >= Wdim - 2) pc[nc++] = 2 * Wdim + 1 - nn;
            float acc = 0.f;
            for (int a = 0; a < nr; ++a) {
                int p = pr[a];
                for (int bb = 0; bb < nc; ++bb) {
                    int qq = pc[bb];
#pragma unroll
                    for (int u = 0; u < 5; ++u) {
                        int rr = p + u - 4;
                        if ((unsigned)rr < (unsigned)Hdim) {
                            int lrr = rr - (r0 - 4);
#pragma unroll
                            for (int v = 0; v < 5; ++v) {
                                int cc = qq + v - 4;
                                if ((unsigned)cc < (unsigned)Wdim)
                                    acc += krs[u * 5 + v] * t1s[lrr][cc - (c0 - 4)];
                            }
                        }
                    }
                }
            }
            float sg = 0.f;
#pragma unroll
            for (int c = 0; c < 9; ++c) {
                int di = c / 3 - 1, dj = c % 3 - 1;
                int rr = m - di, cc = nn - dj;
                if ((unsigned)rr < (unsigned)Hdim && (unsigned)cc < (unsigned)Wdim)
                    sg += fb[(size_t)c * HW + (size_t)rr * Wdim + cc]
                        * u2s[rr - (r0 - 1)][cc - (c0 - 1)];
            }
            qo[o] = acc + lam * sg;
        }
        q0 = qo[0]; q1 = qo[1]; q2 = qo[2]; q3 = qo[3];
    }
    *(float4*)(q + bHW + (size_t)m * Wdim + n) = make_float4(q0, q1, q2, q3);

    float dq = ds[trr + 6][tcc + 6] * q0 + ds[trr + 6][tcc + 7] * q1
             + ds[trr + 6][tcc + 8] * q2 + ds[trr + 6][tcc + 9] * q3;
    red[tid] = dq; __syncthreads();
    for (int st = 64; st > 0; st >>= 1) {
        if (tid < st) red[tid] += red[tid + st];
        __syncthreads();
    }
    if (tid == 0) dqp[b * NTB + bx] = red[0];
}

// ---------- K2: alpha ; x += a d ; r -= a q ; rr partials ----------

__global__ __launch_bounds__(256) void K2(const float* __restrict__ dqp,
                                          const float* __restrict__ deltaN, const int* __restrict__ convN,
                                          const float* __restrict__ dvec, const float* __restrict__ q,
                                          float* __restrict__ x, float* __restrict__ r,
                                          float* __restrict__ rrp) {
    int b = blockIdx.y;
    float s = 0.f;
    for (int e = threadIdx.x; e < NTB; e += 256) s += dqp[b * NTB + e];
    s = blockReduceSum256(s);
    float a = convN[b] ? 0.f : deltaN[b] / s;

    size_t off = (size_t)b * HW + ((size_t)blockIdx.x * 256 + threadIdx.x) * 2;
    float2 dv = *(const float2*)(dvec + off);
    float2 qv = *(const float2*)(q + off);
    float2 xv = *(const float2*)(x + off);
    float2 rv = *(const float2*)(r + off);
    xv.x += a * dv.x; xv.y += a * dv.y;
    rv.x -= a * qv.x; rv.y -= a * qv.y;
    *(float2*)(x + off) = xv;
    *(float2*)(r + off) = rv;
    float ps = blockReduceSum256(rv.x * rv.x + rv.y * rv.y);
    if (threadIdx.x == 0) rrp[b * NTB + blockIdx.x] = ps;
}

// ---------- launch ----------

extern "C" void kernel_launch(void* const* d_in, const int* in_sizes, int n_in,
                              void* d_out, int out_size, void* d_ws, size_t ws_size,
                              hipStream_t stream) {
    const float* y  = (const float*)d_in[0];   // [8,1,384,384]
    const float* kk = (const float*)d_in[1];   // [8,5,5]
    const float* f  = (const float*)d_in[2];   // [8,9,384,384]
    const float* rw = (const float*)d_in[3];   // [1]

    float* x = (float*)d_out;
    float* ws = (float*)d_ws;
    const size_t N = (size_t)Bn * HW;

    float* rden  = ws;
    float* r     = ws + 1 * N;
    float* d0    = ws + 2 * N;
    float* d1    = ws + 3 * N;
    float* q     = ws + 4 * N;
    float* dqp   = ws + 5 * N;                      // Bn*NTB
    float* rrp   = dqp + (size_t)Bn * NTB;          // Bn*NTB
    float* delta = rrp + (size_t)Bn * NTB;          // 2*Bn
    float* thr   = delta + 2 * Bn;                  // Bn
    int*   conv  = (int*)(thr + Bn);                // 2*Bn
    float* dbuf[2] = { d0, d1 };

    dim3 blk256(256), blk128(128);
    dim3 gridT(NTB, Bn);

    k_prep<<<dim3(144, Bn), blk256, 0, stream>>>(f, rden);
    k_init<<<gridT, blk256, 0, stream>>>(y, kk, r, x, rrp);

    for (int t = 0; t < MAXITER; ++t) {
        int np = t & 1, op = np ^ 1;
        K1<<<gridT, blk128, 0, stream>>>(r, dbuf[op], dbuf[np], q, f, rden, kk, rw,
                                         rrp, dqp, delta + op * Bn, delta + np * Bn,
                                         conv + op * Bn, conv + np * Bn, thr, t == 0 ? 1 : 0);
        K2<<<gridT, blk256, 0, stream>>>(dqp, delta + np * Bn, conv + np * Bn,
                                         dbuf[np], q, x, r, rrp);
    }
}

// Round 4
// 2797.185 us; speedup vs baseline: 1.4810x; 1.1661x over previous
//
#include <hip/hip_runtime.h>
#include <math.h>

#define Hdim 384
#define Wdim 384
#define HW (Hdim * Wdim)          // 147456
#define Bn 8
#define MAXITER 50
#define TOLF 1e-6f
#define EPSF 1e-12f

// K1 tiling: 32 wide x 16 tall, 256 threads, 2 px/thread
#define TH 16
#define TW 32
#define NTX 12                    // 384/32 tile cols
#define NTB 288                   // tiles per image (12 x 24)
#define DSH 28                    // TH+12 (halo 6)
#define DSW 44                    // TW+12
#define DSP 45                    // padded stride
#define T1H 24                    // TH+8 (halo 4)
#define T1W 40
#define T1P 41
#define QSP 33

// ---------- helpers ----------

__device__ __forceinline__ int symidx(int t, int n) {
    if (t < 0) t = -t - 1;
    else if (t >= n) t = 2 * n - 1 - t;
    return t;
}

__device__ __forceinline__ float blockReduceSum256(float v) {
    __shared__ float sm[256];
    sm[threadIdx.x] = v;
    __syncthreads();
    for (int s = 128; s > 0; s >>= 1) {
        if (threadIdx.x < s) sm[threadIdx.x] += sm[threadIdx.x + s];
        __syncthreads();
    }
    float r = sm[0];
    __syncthreads();
    return r;
}

// global-memory sym_conv_T (used only in k_init; proven in rounds 1-3)
__device__ float symconvT_s(const float* __restrict__ g, const float* kr, int m, int n) {
    int pr[2]; int nr = 0;
    pr[nr++] = m + 2;
    if (m < 2)         pr[nr++] = 1 - m;
    if (m >= Hdim - 2) pr[nr++] = 2 * Hdim + 1 - m;
    int pc[2]; int nc = 0;
    pc[nc++] = n + 2;
    if (n < 2)         pc[nc++] = 1 - n;
    if (n >= Wdim - 2) pc[nc++] = 2 * Wdim + 1 - n;

    float acc = 0.f;
    for (int a = 0; a < nr; ++a) {
        int p = pr[a];
        for (int bb = 0; bb < nc; ++bb) {
            int q = pc[bb];
#pragma unroll
            for (int u = 0; u < 5; ++u) {
                int rr = p + u - 4;
                if ((unsigned)rr < (unsigned)Hdim) {
                    const float* row = g + rr * Wdim;
#pragma unroll
                    for (int v = 0; v < 5; ++v) {
                        int cc = q + v - 4;
                        if ((unsigned)cc < (unsigned)Wdim)
                            acc += kr[u * 5 + v] * row[cc];
                    }
                }
            }
        }
    }
    return acc;
}

// r = b = K^T y ; x = 0 ; partials of b*b
__global__ __launch_bounds__(256) void k_init(const float* __restrict__ y, const float* __restrict__ kk,
                                              float* __restrict__ r, float* __restrict__ x,
                                              float* __restrict__ part) {
    __shared__ float krs[25];
    int b = blockIdx.y;
    if (threadIdx.x < 25) krs[threadIdx.x] = kk[b * 25 + threadIdx.x];
    __syncthreads();
    int p2 = (blockIdx.x * 256 + threadIdx.x) * 2;
    int m = p2 / Wdim, n = p2 - m * Wdim;
    const float* gb = y + (size_t)b * HW;
    float a0 = symconvT_s(gb, krs, m, n);
    float a1 = symconvT_s(gb, krs, m, n + 1);
    size_t off = (size_t)b * HW + p2;
    r[off] = a0; r[off + 1] = a1;
    x[off] = 0.f; x[off + 1] = 0.f;
    float ps = blockReduceSum256(a0 * a0 + a1 * a1);
    if (threadIdx.x == 0) part[b * NTB + blockIdx.x] = ps;
}

// ---------- K1: fused beta/d-update + A-apply ----------

__global__ __launch_bounds__(256, 4) void K1(
    const float* __restrict__ r, const float* __restrict__ dold,
    float* __restrict__ dnew, float* __restrict__ q,
    const float* __restrict__ f, const float* __restrict__ kk,
    const float* __restrict__ rw,
    const float* __restrict__ rrp, float* __restrict__ dqp,
    const float* __restrict__ deltaOld, float* __restrict__ deltaNew,
    const int* __restrict__ convOld, int* __restrict__ convNew,
    float* __restrict__ thrS, int isFirst)
{
    __shared__ float ds[DSH][DSP];
    __shared__ float t1s[T1H][T1P];
    __shared__ float qs[TH][QSP];
    __shared__ float krs[25];
    __shared__ float red[256];

    int b = blockIdx.y;
    int bx = blockIdx.x;
    int ty = bx / NTX, tx = bx - ty * NTX;
    int r0 = ty * TH, c0 = tx * TW;
    int tid = threadIdx.x;
    size_t bHW = (size_t)b * HW;
    const float* rb = r + bHW;
    const float* db = dold + bHW;
    const float* fb = f + (size_t)b * 9 * HW;

    if (tid < 25) krs[tid] = kk[b * 25 + tid];
    // qs zero init (becomes visible at the sync after t1s)
    for (int e = tid; e < TH * QSP; e += 256) ((float*)qs)[e] = 0.f;

    // ---- early register staging of f over (tile + halo 1): 18x34 = 612 slots ----
    float freg[3][9];
    float u2r[3];
    int sa[3], se[3];
    bool sval[3];
#pragma unroll
    for (int p = 0; p < 3; ++p) {
        int e = p * 256 + tid;
        int a = e / 34, ee = e - a * 34;
        int gr = r0 - 1 + a, gc = c0 - 1 + ee;
        bool v = (e < 612) && ((unsigned)gr < (unsigned)Hdim) && ((unsigned)gc < (unsigned)Wdim);
        sa[p] = a; se[p] = ee; sval[p] = v;
        size_t gg = (size_t)gr * Wdim + gc;
#pragma unroll
        for (int c = 0; c < 9; ++c)
            freg[p][c] = v ? fb[(size_t)c * HW + gg] : 0.f;
    }

    // ---- phase 1: delta = sum(rr partials); beta ----
    float s = 0.f;
    for (int e = tid; e < NTB; e += 256) s += rrp[b * NTB + e];
    red[tid] = s; __syncthreads();
    for (int st = 128; st > 0; st >>= 1) {
        if (tid < st) red[tid] += red[tid + st];
        __syncthreads();
    }
    float delta = red[0];
    __syncthreads();
    float beta = isFirst ? 0.f : delta / deltaOld[b];
    if (bx == 0 && tid == 0) {
        deltaNew[b] = delta;
        if (isFirst) {
            float th = TOLF * delta;
            thrS[b] = th;
            convNew[b] = (delta <= th) ? 1 : 0;
        } else {
            convNew[b] = (convOld[b] || delta <= thrS[b]) ? 1 : 0;
        }
    }

    // ---- phase 2: ds = r + beta*d_old (tile + halo 6; OOB -> 0) ----
    for (int e = tid; e < DSH * DSW; e += 256) {
        int lr = e / DSW, lc = e - lr * DSW;
        int gr = r0 - 6 + lr, gc = c0 - 6 + lc;
        float v = 0.f;
        if ((unsigned)gr < (unsigned)Hdim && (unsigned)gc < (unsigned)Wdim) {
            size_t gg = (size_t)gr * Wdim + gc;
            v = rb[gg];
            if (!isFirst) v += beta * db[gg];
        }
        ds[lr][lc] = v;
    }
    __syncthreads();

    int trr = tid >> 4;               // 0..15
    int tcc = (tid & 15) << 1;        // 0,2,...,30
    // write own 2 px of d_new
    {
        float2 dv = make_float2(ds[trr + 6][tcc + 6], ds[trr + 6][tcc + 7]);
        *(float2*)(dnew + bHW + (size_t)(r0 + trr) * Wdim + c0 + tcc) = dv;
    }

    // ---- phase 3: u2 at owned source positions (registers) ----
#pragma unroll
    for (int p = 0; p < 3; ++p) {
        if (sval[p]) {
            float acc = 0.f, sab = 0.f;
#pragma unroll
            for (int c = 0; c < 9; ++c) {
                acc += freg[p][c] * ds[sa[p] + c / 3 + 4][se[p] + c % 3 + 4];
                sab += fabsf(freg[p][c]);
            }
            float rd = 1.f / fmaxf(sab, EPSF);
            u2r[p] = rd * rd * acc;
        } else {
            u2r[p] = 0.f;
        }
    }

    bool interior = (r0 >= 16 && r0 <= 352 && c0 >= 32 && c0 <= 320);

    // ---- phase 4: t1 = sym_conv(d)  (tile + halo 4) ----
    if (interior) {
        for (int e = tid; e < 240; e += 256) {
            int lr = e / 10, lc4 = (e - lr * 10) * 4;
            float a0 = 0, a1 = 0, a2 = 0, a3 = 0;
#pragma unroll
            for (int u = 0; u < 5; ++u) {
                const float* drow = &ds[lr + 4 - u][lc4];
                float w[8];
#pragma unroll
                for (int z = 0; z < 8; ++z) w[z] = drow[z];
#pragma unroll
                for (int v = 0; v < 5; ++v) {
                    float kv = krs[u * 5 + v];
                    a0 += kv * w[4 - v]; a1 += kv * w[5 - v];
                    a2 += kv * w[6 - v]; a3 += kv * w[7 - v];
                }
            }
            t1s[lr][lc4] = a0; t1s[lr][lc4 + 1] = a1;
            t1s[lr][lc4 + 2] = a2; t1s[lr][lc4 + 3] = a3;
        }
    } else {
        for (int e = tid; e < T1H * T1W; e += 256) {
            int lr = e / T1W, lc = e - lr * T1W;
            int gi = r0 - 4 + lr, gj = c0 - 4 + lc;
            float v = 0.f;
            if ((unsigned)gi < (unsigned)Hdim && (unsigned)gj < (unsigned)Wdim) {
                float acc = 0.f;
#pragma unroll
                for (int u = 0; u < 5; ++u) {
                    int rr = symidx(gi + 2 - u, Hdim) - (r0 - 6);
#pragma unroll
                    for (int vv = 0; vv < 5; ++vv) {
                        int cc = symidx(gj + 2 - vv, Wdim) - (c0 - 6);
                        acc += krs[u * 5 + vv] * ds[rr][cc];
                    }
                }
                v = acc;
            }
            t1s[lr][lc] = v;
        }
    }
    __syncthreads();     // t1s + qs-init visible

    // ---- phase 5a: scatter adjoint KPN: qs[s+dc] += f[c,s]*u2(s), 9 rounds ----
#pragma unroll
    for (int c = 0; c < 9; ++c) {
        int di = c / 3, dj = c % 3;   // raw 0..2; target = sa+di-2, se+dj-2
#pragma unroll
        for (int p = 0; p < 3; ++p) {
            int tr = sa[p] + di - 2;
            int tc = se[p] + dj - 2;
            if ((unsigned)tr < (unsigned)TH && (unsigned)tc < (unsigned)TW)
                qs[tr][tc] += freg[p][c] * u2r[p];
        }
        __syncthreads();
    }

    // ---- phase 5b: q = sym_conv_T(t1) + lam * qs ; dq partials ----
    float lam = expf(rw[0]);
    int m = r0 + trr, n = c0 + tcc;
    float q0, q1;
    if (interior) {
        float a0 = 0, a1 = 0;
#pragma unroll
        for (int u = 0; u < 5; ++u) {
            const float* t1row = &t1s[trr + 2 + u][tcc + 2];
            float w[6];
#pragma unroll
            for (int z = 0; z < 6; ++z) w[z] = t1row[z];
#pragma unroll
            for (int v = 0; v < 5; ++v) {
                float kv = krs[u * 5 + v];
                a0 += kv * w[v]; a1 += kv * w[v + 1];
            }
        }
        q0 = a0; q1 = a1;
    } else {
        float qo[2];
#pragma unroll
        for (int o = 0; o < 2; ++o) {
            int nn = n + o;
            int pr[2]; int nr = 0;
            pr[nr++] = m + 2;
            if (m < 2)         pr[nr++] = 1 - m;
            if (m >= Hdim - 2) pr[nr++] = 2 * Hdim + 1 - m;
            int pc[2]; int nc = 0;
            pc[nc++] = nn + 2;
            if (nn < 2)         pc[nc++] = 1 - nn;
            if (nn >= Wdim - 2) pc[nc++] = 2 * Wdim + 1 - nn;
            float acc = 0.f;
            for (int a = 0; a < nr; ++a) {
                int p = pr[a];
                for (int bb = 0; bb < nc; ++bb) {
                    int qq = pc[bb];
#pragma unroll
                    for (int u = 0; u < 5; ++u) {
                        int rr = p + u - 4;
                        if ((unsigned)rr < (unsigned)Hdim) {
                            int lrr = rr - (r0 - 4);
#pragma unroll
                            for (int v = 0; v < 5; ++v) {
                                int cc = qq + v - 4;
                                if ((unsigned)cc < (unsigned)Wdim)
                                    acc += krs[u * 5 + v] * t1s[lrr][cc - (c0 - 4)];
                            }
                        }
                    }
                }
            }
            qo[o] = acc;
        }
        q0 = qo[0]; q1 = qo[1];
    }
    q0 += lam * qs[trr][tcc];
    q1 += lam * qs[trr][tcc + 1];
    *(float2*)(q + bHW + (size_t)m * Wdim + n) = make_float2(q0, q1);

    float dq = ds[trr + 6][tcc + 6] * q0 + ds[trr + 6][tcc + 7] * q1;
    red[tid] = dq; __syncthreads();
    for (int st = 128; st > 0; st >>= 1) {
        if (tid < st) red[tid] += red[tid + st];
        __syncthreads();
    }
    if (tid == 0) dqp[b * NTB + bx] = red[0];
}

// ---------- K2: alpha ; x += a d ; r -= a q ; rr partials ----------

__global__ __launch_bounds__(256) void K2(const float* __restrict__ dqp,
                                          const float* __restrict__ deltaN, const int* __restrict__ convN,
                                          const float* __restrict__ dvec, const float* __restrict__ q,
                                          float* __restrict__ x, float* __restrict__ r,
                                          float* __restrict__ rrp) {
    int b = blockIdx.y;
    float s = 0.f;
    for (int e = threadIdx.x; e < NTB; e += 256) s += dqp[b * NTB + e];
    s = blockReduceSum256(s);
    float a = convN[b] ? 0.f : deltaN[b] / s;

    size_t off = (size_t)b * HW + ((size_t)blockIdx.x * 256 + threadIdx.x) * 2;
    float2 dv = *(const float2*)(dvec + off);
    float2 qv = *(const float2*)(q + off);
    float2 xv = *(const float2*)(x + off);
    float2 rv = *(const float2*)(r + off);
    xv.x += a * dv.x; xv.y += a * dv.y;
    rv.x -= a * qv.x; rv.y -= a * qv.y;
    *(float2*)(x + off) = xv;
    *(float2*)(r + off) = rv;
    float ps = blockReduceSum256(rv.x * rv.x + rv.y * rv.y);
    if (threadIdx.x == 0) rrp[b * NTB + blockIdx.x] = ps;
}

// ---------- launch ----------

extern "C" void kernel_launch(void* const* d_in, const int* in_sizes, int n_in,
                              void* d_out, int out_size, void* d_ws, size_t ws_size,
                              hipStream_t stream) {
    const float* y  = (const float*)d_in[0];   // [8,1,384,384]
    const float* kk = (const float*)d_in[1];   // [8,5,5]
    const float* f  = (const float*)d_in[2];   // [8,9,384,384]
    const float* rw = (const float*)d_in[3];   // [1]

    float* x = (float*)d_out;
    float* ws = (float*)d_ws;
    const size_t N = (size_t)Bn * HW;

    float* r     = ws;
    float* d0    = ws + 1 * N;
    float* d1    = ws + 2 * N;
    float* q     = ws + 3 * N;
    float* dqp   = ws + 4 * N;                      // Bn*NTB
    float* rrp   = dqp + (size_t)Bn * NTB;          // Bn*NTB
    float* delta = rrp + (size_t)Bn * NTB;          // 2*Bn
    float* thr   = delta + 2 * Bn;                  // Bn
    int*   conv  = (int*)(thr + Bn);                // 2*Bn
    float* dbuf[2] = { d0, d1 };

    dim3 blk256(256);
    dim3 gridT(NTB, Bn);

    k_init<<<gridT, blk256, 0, stream>>>(y, kk, r, x, rrp);

    for (int t = 0; t < MAXITER; ++t) {
        int np = t & 1, op = np ^ 1;
        K1<<<gridT, blk256, 0, stream>>>(r, dbuf[op], dbuf[np], q, f, kk, rw,
                                         rrp, dqp, delta + op * Bn, delta + np * Bn,
                                         conv + op * Bn, conv + np * Bn, thr, t == 0 ? 1 : 0);
        K2<<<gridT, blk256, 0, stream>>>(dqp, delta + np * Bn, conv + np * Bn,
                                         dbuf[np], q, x, r, rrp);
    }
}

// Round 6
// 2592.406 us; speedup vs baseline: 1.5980x; 1.0790x over previous
//
#include <hip/hip_runtime.h>
#include <math.h>

#define Hdim 384
#define Wdim 384
#define HW (Hdim * Wdim)          // 147456
#define Bn 8
#define MAXITER 50
#define TOLF 1e-6f
#define EPSF 1e-12f

#define NPB 288                   // partial-array width per image (k_init, K2 rr, dqb)
#define NZ0 144                   // z0 (KtK) blocks per image: 12x12 tiles of 32x32
#define NZ1 288                   // z1 (LtL) blocks per image: 24x12 tiles of 16x32

// z0 LDS geometry (32x32 tile)
#define DSH 44
#define DSW 44
#define DSP 45
#define T1H 40
#define T1W 40
#define T1P 41

struct Z0S { float ds[DSH][DSP]; float t1s[T1H][T1P]; };   // 14480 B
struct Z1S { float dsm[20][37]; float qs[16][33]; };       //  5072 B
union SMemU { Z0S z0; Z1S z1; };

// ---------- helpers ----------

__device__ __forceinline__ int symidx(int t, int n) {
    if (t < 0) t = -t - 1;
    else if (t >= n) t = 2 * n - 1 - t;
    return t;
}

__device__ __forceinline__ float blockReduceSum256(float v) {
    __shared__ float sm[256];
    sm[threadIdx.x] = v;
    __syncthreads();
    for (int s = 128; s > 0; s >>= 1) {
        if (threadIdx.x < s) sm[threadIdx.x] += sm[threadIdx.x + s];
        __syncthreads();
    }
    float r = sm[0];
    __syncthreads();
    return r;
}

// global-memory sym_conv_T (k_init only; proven rounds 1-4)
__device__ float symconvT_s(const float* __restrict__ g, const float* kr, int m, int n) {
    int pr[2]; int nr = 0;
    pr[nr++] = m + 2;
    if (m < 2)         pr[nr++] = 1 - m;
    if (m >= Hdim - 2) pr[nr++] = 2 * Hdim + 1 - m;
    int pc[2]; int nc = 0;
    pc[nc++] = n + 2;
    if (n < 2)         pc[nc++] = 1 - n;
    if (n >= Wdim - 2) pc[nc++] = 2 * Wdim + 1 - n;

    float acc = 0.f;
    for (int a = 0; a < nr; ++a) {
        int p = pr[a];
        for (int bb = 0; bb < nc; ++bb) {
            int q = pc[bb];
#pragma unroll
            for (int u = 0; u < 5; ++u) {
                int rr = p + u - 4;
                if ((unsigned)rr < (unsigned)Hdim) {
                    const float* row = g + rr * Wdim;
#pragma unroll
                    for (int v = 0; v < 5; ++v) {
                        int cc = q + v - 4;
                        if ((unsigned)cc < (unsigned)Wdim)
                            acc += kr[u * 5 + v] * row[cc];
                    }
                }
            }
        }
    }
    return acc;
}

// r = b = K^T y ; x = 0 ; partials of b*b (288 blocks/image, 2 px/thread)
__global__ __launch_bounds__(256) void k_init(const float* __restrict__ y, const float* __restrict__ kk,
                                              float* __restrict__ r, float* __restrict__ x,
                                              float* __restrict__ part) {
    __shared__ float krs[25];
    int b = blockIdx.y;
    if (threadIdx.x < 25) krs[threadIdx.x] = kk[b * 25 + threadIdx.x];
    __syncthreads();
    int p2 = (blockIdx.x * 256 + threadIdx.x) * 2;
    int m = p2 / Wdim, n = p2 - m * Wdim;
    const float* gb = y + (size_t)b * HW;
    float a0 = symconvT_s(gb, krs, m, n);
    float a1 = symconvT_s(gb, krs, m, n + 1);
    size_t off = (size_t)b * HW + p2;
    r[off] = a0; r[off + 1] = a1;
    x[off] = 0.f; x[off + 1] = 0.f;
    float ps = blockReduceSum256(a0 * a0 + a1 * a1);
    if (threadIdx.x == 0) part[b * NPB + blockIdx.x] = ps;
}

// ---------- K1: role-split  (z0: beta/d-build + K^TK ; z1: L^TL) ----------

__global__ __launch_bounds__(256, 4) void K1(
    const float* __restrict__ r, const float* __restrict__ dold, float* __restrict__ dnew,
    float* __restrict__ qa, float* __restrict__ qb,
    const float* __restrict__ f, const float* __restrict__ kk,
    const float* __restrict__ rrp, float* __restrict__ dqa, float* __restrict__ dqb,
    const float* __restrict__ deltaO, float* __restrict__ deltaN,
    const int* __restrict__ convO, int* __restrict__ convN,
    float* __restrict__ thrS, int isFirst)
{
    __shared__ SMemU sm;
    __shared__ float red[256];
    __shared__ float krs[25];

    int b = blockIdx.y, bxg = blockIdx.x, tid = threadIdx.x;
    bool roleK = (bxg < NZ0);
    size_t bHW = (size_t)b * HW;
    const float* rb = r + bHW;
    const float* db = dold + bHW;

    // ---- batched preload (issued before the reduce for latency overlap) ----
    float rv[8], dv[8];
    float freg[3][9];
    int r0, c0;
    if (roleK) {
        int ty = bxg / 12, tx = bxg - ty * 12;
        r0 = ty * 32; c0 = tx * 32;
        if (tid < 25) krs[tid] = kk[b * 25 + tid];
#pragma unroll
        for (int p = 0; p < 8; ++p) {
            int e = p * 256 + tid;
            int a = e / 44, ee = e - a * 44;
            int gr = r0 - 6 + a, gc = c0 - 6 + ee;
            bool v = (e < 1936) && ((unsigned)gr < (unsigned)Hdim) && ((unsigned)gc < (unsigned)Wdim);
            size_t gg = (size_t)gr * Wdim + gc;
            rv[p] = v ? rb[gg] : 0.f;
            dv[p] = (v && !isFirst) ? db[gg] : 0.f;
        }
    } else {
        int bxl = bxg - NZ0;
        int ty = bxl / 12, tx = bxl - ty * 12;
        r0 = ty * 16; c0 = tx * 32;
        const float* fb = f + (size_t)b * 9 * HW;
#pragma unroll
        for (int p = 0; p < 3; ++p) {
            int e = p * 256 + tid;
            int a = e / 34, ee = e - a * 34;
            int gr = r0 - 1 + a, gc = c0 - 1 + ee;
            bool v = (e < 612) && ((unsigned)gr < (unsigned)Hdim) && ((unsigned)gc < (unsigned)Wdim);
            size_t gg = (size_t)gr * Wdim + gc;
#pragma unroll
            for (int c = 0; c < 9; ++c)
                freg[p][c] = v ? fb[(size_t)c * HW + gg] : 0.f;
        }
#pragma unroll
        for (int p = 0; p < 3; ++p) {
            int e = p * 256 + tid;
            int a = e / 36, ee = e - a * 36;
            int gr = r0 - 2 + a, gc = c0 - 2 + ee;
            bool v = (e < 720) && ((unsigned)gr < (unsigned)Hdim) && ((unsigned)gc < (unsigned)Wdim);
            size_t gg = (size_t)gr * Wdim + gc;
            rv[p] = v ? rb[gg] : 0.f;
            dv[p] = (v && !isFirst) ? db[gg] : 0.f;
        }
    }

    // ---- beta reduce (identical tree in every block -> identical bits) ----
    float s = rrp[b * NPB + tid] + ((tid < 32) ? rrp[b * NPB + 256 + tid] : 0.f);
    red[tid] = s; __syncthreads();
    for (int st = 128; st > 0; st >>= 1) {
        if (tid < st) red[tid] += red[tid + st];
        __syncthreads();
    }
    float delta = red[0];
    __syncthreads();
    float beta = isFirst ? 0.f : delta / deltaO[b];
    if (bxg == 0 && tid == 0) {
        deltaN[b] = delta;
        if (isFirst) {
            float th = TOLF * delta;
            thrS[b] = th;
            convN[b] = (delta <= th) ? 1 : 0;
        } else {
            convN[b] = (convO[b] || delta <= thrS[b]) ? 1 : 0;
        }
    }

    if (roleK) {
        // ---- z0: ds = d_new over tile+halo6 from regs ----
#pragma unroll
        for (int p = 0; p < 8; ++p) {
            int e = p * 256 + tid;
            if (e < 1936) {
                int a = e / 44, ee = e - a * 44;
                sm.z0.ds[a][ee] = isFirst ? rv[p] : rv[p] + beta * dv[p];
            }
        }
        __syncthreads();

        int trr = tid >> 3, tcc = (tid & 7) << 2;
        size_t ooff = bHW + (size_t)(r0 + trr) * Wdim + c0 + tcc;
        float4 dn4 = make_float4(sm.z0.ds[trr + 6][tcc + 6], sm.z0.ds[trr + 6][tcc + 7],
                                 sm.z0.ds[trr + 6][tcc + 8], sm.z0.ds[trr + 6][tcc + 9]);
        *(float4*)(dnew + ooff) = dn4;

        bool interior = (r0 >= 32 && r0 <= 320 && c0 >= 32 && c0 <= 320);

        // ---- t1 = sym_conv(d) over tile + halo 4 ----
        if (interior) {
            for (int e = tid; e < 400; e += 256) {
                int lr = e / 10, lc4 = (e - lr * 10) * 4;
                float a0 = 0, a1 = 0, a2 = 0, a3 = 0;
#pragma unroll
                for (int u = 0; u < 5; ++u) {
                    const float* drow = &sm.z0.ds[lr + 4 - u][lc4];
                    float w[8];
#pragma unroll
                    for (int z = 0; z < 8; ++z) w[z] = drow[z];
#pragma unroll
                    for (int v = 0; v < 5; ++v) {
                        float kv = krs[u * 5 + v];
                        a0 += kv * w[4 - v]; a1 += kv * w[5 - v];
                        a2 += kv * w[6 - v]; a3 += kv * w[7 - v];
                    }
                }
                sm.z0.t1s[lr][lc4] = a0; sm.z0.t1s[lr][lc4 + 1] = a1;
                sm.z0.t1s[lr][lc4 + 2] = a2; sm.z0.t1s[lr][lc4 + 3] = a3;
            }
        } else {
            for (int e = tid; e < T1H * T1W; e += 256) {
                int lr = e / T1W, lc = e - lr * T1W;
                int gi = r0 - 4 + lr, gj = c0 - 4 + lc;
                float v = 0.f;
                if ((unsigned)gi < (unsigned)Hdim && (unsigned)gj < (unsigned)Wdim) {
                    float acc = 0.f;
#pragma unroll
                    for (int u = 0; u < 5; ++u) {
                        int rr = symidx(gi + 2 - u, Hdim) - (r0 - 6);
#pragma unroll
                        for (int vv = 0; vv < 5; ++vv) {
                            int cc = symidx(gj + 2 - vv, Wdim) - (c0 - 6);
                            acc += krs[u * 5 + vv] * sm.z0.ds[rr][cc];
                        }
                    }
                    v = acc;
                }
                sm.z0.t1s[lr][lc] = v;
            }
        }
        __syncthreads();

        // ---- qa = sym_conv_T(t1) ; dq_a partials ----
        int m = r0 + trr, n = c0 + tcc;
        float q0, q1, q2, q3;
        if (interior) {
            float a0 = 0, a1 = 0, a2 = 0, a3 = 0;
#pragma unroll
            for (int u = 0; u < 5; ++u) {
                const float* t1row = &sm.z0.t1s[trr + 2 + u][tcc + 2];
                float w[8];
#pragma unroll
                for (int z = 0; z < 8; ++z) w[z] = t1row[z];
#pragma unroll
                for (int v = 0; v < 5; ++v) {
                    float kv = krs[u * 5 + v];
                    a0 += kv * w[v]; a1 += kv * w[v + 1];
                    a2 += kv * w[v + 2]; a3 += kv * w[v + 3];
                }
            }
            q0 = a0; q1 = a1; q2 = a2; q3 = a3;
        } else {
            float qo[4];
#pragma unroll
            for (int o = 0; o < 4; ++o) {
                int nn = n + o;
                int pr[2]; int nr = 0;
                pr[nr++] = m + 2;
                if (m < 2)         pr[nr++] = 1 - m;
                if (m >= Hdim - 2) pr[nr++] = 2 * Hdim + 1 - m;
                int pc[2]; int nc = 0;
                pc[nc++] = nn + 2;
                if (nn < 2)         pc[nc++] = 1 - nn;
                if (nn >= Wdim - 2) pc[nc++] = 2 * Wdim + 1 - nn;
                float acc = 0.f;
                for (int a = 0; a < nr; ++a) {
                    int p = pr[a];
                    for (int bb = 0; bb < nc; ++bb) {
                        int qq2 = pc[bb];
#pragma unroll
                        for (int u = 0; u < 5; ++u) {
                            int rr = p + u - 4;
                            if ((unsigned)rr < (unsigned)Hdim) {
                                int lrr = rr - (r0 - 4);
#pragma unroll
                                for (int v = 0; v < 5; ++v) {
                                    int cc = qq2 + v - 4;
                                    if ((unsigned)cc < (unsigned)Wdim)
                                        acc += krs[u * 5 + v] * sm.z0.t1s[lrr][cc - (c0 - 4)];
                                }
                            }
                        }
                    }
                }
                qo[o] = acc;
            }
            q0 = qo[0]; q1 = qo[1]; q2 = qo[2]; q3 = qo[3];
        }
        *(float4*)(qa + ooff) = make_float4(q0, q1, q2, q3);

        float pdq = dn4.x * q0 + dn4.y * q1 + dn4.z * q2 + dn4.w * q3;
        red[tid] = pdq; __syncthreads();
        for (int st = 128; st > 0; st >>= 1) {
            if (tid < st) red[tid] += red[tid + st];
            __syncthreads();
        }
        if (tid == 0) dqa[b * NZ0 + bxg] = red[0];

    } else {
        int bxl = bxg - NZ0;
        // qs zero-init + dsm fill from regs
        for (int e = tid; e < 16 * 33; e += 256) ((float*)sm.z1.qs)[e] = 0.f;
#pragma unroll
        for (int p = 0; p < 3; ++p) {
            int e = p * 256 + tid;
            if (e < 720) {
                int a = e / 36, ee = e - a * 36;
                sm.z1.dsm[a][ee] = isFirst ? rv[p] : rv[p] + beta * dv[p];
            }
        }
        __syncthreads();

        // u2 at 18x34 source slots (invalid slots: freg=0 -> uv=0)
        float u2r[3];
#pragma unroll
        for (int p = 0; p < 3; ++p) {
            int e = p * 256 + tid;
            float uv = 0.f;
            if (e < 612) {
                int sa = e / 34, se = e - sa * 34;
                float acc = 0.f, sab = 0.f;
#pragma unroll
                for (int c = 0; c < 9; ++c) {
                    acc += freg[p][c] * sm.z1.dsm[sa + c / 3][se + c % 3];
                    sab += fabsf(freg[p][c]);
                }
                float rd = 1.f / fmaxf(sab, EPSF);
                uv = rd * rd * acc;
            }
            u2r[p] = uv;
        }
        __syncthreads();

        // scatter adjoint KPN into qs (9 race-free rounds)
#pragma unroll
        for (int c = 0; c < 9; ++c) {
            int di = c / 3, dj = c % 3;
#pragma unroll
            for (int p = 0; p < 3; ++p) {
                int e = p * 256 + tid;
                if (e < 612) {
                    int sa = e / 34, se = e - sa * 34;
                    int tr = sa + di - 2, tc = se + dj - 2;
                    if ((unsigned)tr < 16u && (unsigned)tc < 32u)
                        sm.z1.qs[tr][tc] += freg[p][c] * u2r[p];
                }
            }
            __syncthreads();
        }

        int trr = tid >> 4, tcc = (tid & 15) << 1;
        size_t ooff = bHW + (size_t)(r0 + trr) * Wdim + c0 + tcc;
        float q0 = sm.z1.qs[trr][tcc], q1 = sm.z1.qs[trr][tcc + 1];
        *(float2*)(qb + ooff) = make_float2(q0, q1);
        float d0 = sm.z1.dsm[trr + 2][tcc + 2], d1 = sm.z1.dsm[trr + 2][tcc + 3];
        float pdq = d0 * q0 + d1 * q1;
        red[tid] = pdq; __syncthreads();
        for (int st = 128; st > 0; st >>= 1) {
            if (tid < st) red[tid] += red[tid + st];
            __syncthreads();
        }
        if (tid == 0) dqb[b * NZ1 + bxl] = red[0];
    }
}

// ---------- K2: alpha ; q=qa+lam*qb ; x += a d ; r -= a q ; rr partials ----------

__global__ __launch_bounds__(256) void K2(
    const float* __restrict__ dqa, const float* __restrict__ dqb, const float* __restrict__ rw,
    const float* __restrict__ deltaN, const int* __restrict__ convN,
    const float* __restrict__ d, const float* __restrict__ qa, const float* __restrict__ qb,
    float* __restrict__ x, float* __restrict__ r, float* __restrict__ rrp)
{
    __shared__ float red[512];
    int b = blockIdx.y, bx = blockIdx.x, tid = threadIdx.x;
    float sA = (tid < NZ0) ? dqa[b * NZ0 + tid] : 0.f;
    float sB = dqb[b * NZ1 + tid] + ((tid < 32) ? dqb[b * NZ1 + 256 + tid] : 0.f);
    red[tid] = sA; red[256 + tid] = sB;
    __syncthreads();
    for (int st = 128; st > 0; st >>= 1) {
        if (tid < st) { red[tid] += red[tid + st]; red[256 + tid] += red[256 + tid + st]; }
        __syncthreads();
    }
    float lam = expf(rw[0]);
    float dq = red[0] + lam * red[256];
    float a = convN[b] ? 0.f : deltaN[b] / dq;
    __syncthreads();

    size_t off = (size_t)b * HW + ((size_t)bx * 256 + tid) * 2;
    float2 d2  = *(const float2*)(d + off);
    float2 qa2 = *(const float2*)(qa + off);
    float2 qb2 = *(const float2*)(qb + off);
    float2 xv  = *(float2*)(x + off);
    float2 rv  = *(float2*)(r + off);
    float q0 = qa2.x + lam * qb2.x, q1 = qa2.y + lam * qb2.y;
    xv.x += a * d2.x; xv.y += a * d2.y;
    rv.x -= a * q0;   rv.y -= a * q1;
    *(float2*)(x + off) = xv;
    *(float2*)(r + off) = rv;

    float ps = rv.x * rv.x + rv.y * rv.y;
    red[tid] = ps; __syncthreads();
    for (int st = 128; st > 0; st >>= 1) {
        if (tid < st) red[tid] += red[tid + st];
        __syncthreads();
    }
    if (tid == 0) rrp[b * NPB + bx] = red[0];
}

// ---------- launch ----------

extern "C" void kernel_launch(void* const* d_in, const int* in_sizes, int n_in,
                              void* d_out, int out_size, void* d_ws, size_t ws_size,
                              hipStream_t stream) {
    const float* y  = (const float*)d_in[0];   // [8,1,384,384]
    const float* kk = (const float*)d_in[1];   // [8,5,5]
    const float* f  = (const float*)d_in[2];   // [8,9,384,384]
    const float* rw = (const float*)d_in[3];   // [1]

    float* x = (float*)d_out;
    float* ws = (float*)d_ws;
    const size_t N = (size_t)Bn * HW;

    float* r   = ws;
    float* d0  = ws + 1 * N;
    float* d1  = ws + 2 * N;
    float* qa  = ws + 3 * N;
    float* qb  = ws + 4 * N;
    float* P   = ws + 5 * N;
    float* dqa = P;                       P += (size_t)Bn * NZ0;
    float* dqb = P;                       P += (size_t)Bn * NZ1;
    float* rrp = P;                       P += (size_t)Bn * NPB;
    float* delta = P;                     P += 2 * Bn;
    float* thr   = P;                     P += Bn;
    int*   conv  = (int*)P;
    float* db[2] = { d0, d1 };

    dim3 blk(256);

    k_init<<<dim3(NPB, Bn), blk, 0, stream>>>(y, kk, r, x, rrp);

    for (int t = 0; t < MAXITER; ++t) {
        int i = t & 1, o = i ^ 1;
        K1<<<dim3(NZ0 + NZ1, Bn), blk, 0, stream>>>(
            r, db[i], db[o], qa, qb, f, kk,
            rrp, dqa, dqb,
            delta + i * Bn, delta + o * Bn,
            conv + i * Bn, conv + o * Bn,
            thr, t == 0 ? 1 : 0);
        K2<<<dim3(NPB, Bn), blk, 0, stream>>>(
            dqa, dqb, rw, delta + o * Bn, conv + o * Bn,
            db[o], qa, qb, x, r, rrp);
    }
}

// Round 7
// 2237.186 us; speedup vs baseline: 1.8517x; 1.1588x over previous
//
#include <hip/hip_runtime.h>
#include <math.h>

#define Hdim 384
#define Wdim 384
#define HW (Hdim * Wdim)          // 147456
#define Bn 8
#define MAXITER 50
#define TOLF 1e-6f
#define EPSF 1e-12f

#define NPB 288                   // partial-array width per image (k_init, K2 rr)
#define NZ0 144                   // z0 (KtK) blocks per image: 12x12 tiles of 32x32
#define NZ1 288                   // z1 (LtL) blocks per image: 24x12 tiles of 16x32

// z0 LDS geometry (32x32 tile)
#define DSH 44
#define DSW 44
#define DSP 45
#define T1H 40
#define T1W 40
#define T1P 41

struct Z0S { float ds[DSH][DSP]; float t1s[T1H][T1P]; };   // 14480 B
struct Z1S { float dsm[20][37]; float qs[16][33]; };       //  5072 B
union SMemU { Z0S z0; Z1S z1; };

// ---------- helpers ----------

__device__ __forceinline__ int symidx(int t, int n) {
    if (t < 0) t = -t - 1;
    else if (t >= n) t = 2 * n - 1 - t;
    return t;
}

__device__ __forceinline__ float blockReduceSum256(float v) {
    __shared__ float sm[256];
    sm[threadIdx.x] = v;
    __syncthreads();
    for (int s = 128; s > 0; s >>= 1) {
        if (threadIdx.x < s) sm[threadIdx.x] += sm[threadIdx.x + s];
        __syncthreads();
    }
    float r = sm[0];
    __syncthreads();
    return r;
}

// global-memory sym_conv_T (k_init only; proven rounds 1-6)
__device__ float symconvT_s(const float* __restrict__ g, const float* kr, int m, int n) {
    int pr[2]; int nr = 0;
    pr[nr++] = m + 2;
    if (m < 2)         pr[nr++] = 1 - m;
    if (m >= Hdim - 2) pr[nr++] = 2 * Hdim + 1 - m;
    int pc[2]; int nc = 0;
    pc[nc++] = n + 2;
    if (n < 2)         pc[nc++] = 1 - n;
    if (n >= Wdim - 2) pc[nc++] = 2 * Wdim + 1 - n;

    float acc = 0.f;
    for (int a = 0; a < nr; ++a) {
        int p = pr[a];
        for (int bb = 0; bb < nc; ++bb) {
            int q = pc[bb];
#pragma unroll
            for (int u = 0; u < 5; ++u) {
                int rr = p + u - 4;
                if ((unsigned)rr < (unsigned)Hdim) {
                    const float* row = g + rr * Wdim;
#pragma unroll
                    for (int v = 0; v < 5; ++v) {
                        int cc = q + v - 4;
                        if ((unsigned)cc < (unsigned)Wdim)
                            acc += kr[u * 5 + v] * row[cc];
                    }
                }
            }
        }
    }
    return acc;
}

// r = b = K^T y ; x = 0 ; partials of b*b (288 blocks/image, 2 px/thread)
__global__ __launch_bounds__(256) void k_init(const float* __restrict__ y, const float* __restrict__ kk,
                                              float* __restrict__ r, float* __restrict__ x,
                                              float* __restrict__ part) {
    __shared__ float krs[25];
    int b = blockIdx.y;
    if (threadIdx.x < 25) krs[threadIdx.x] = kk[b * 25 + threadIdx.x];
    __syncthreads();
    int p2 = (blockIdx.x * 256 + threadIdx.x) * 2;
    int m = p2 / Wdim, n = p2 - m * Wdim;
    const float* gb = y + (size_t)b * HW;
    float a0 = symconvT_s(gb, krs, m, n);
    float a1 = symconvT_s(gb, krs, m, n + 1);
    size_t off = (size_t)b * HW + p2;
    r[off] = a0; r[off + 1] = a1;
    x[off] = 0.f; x[off + 1] = 0.f;
    float ps = blockReduceSum256(a0 * a0 + a1 * a1);
    if (threadIdx.x == 0) part[b * NPB + blockIdx.x] = ps;
}

// kern = fp16( f * (1/max(sum|f|,eps)) )  — the reference's l1_normalize(f)
__global__ __launch_bounds__(256) void k_prep(const float* __restrict__ f, _Float16* __restrict__ kh) {
    int id = blockIdx.x;
    int b = id & 7;
    int base = (id >> 3) * 512 + threadIdx.x * 2;
    const float* fb = f + (size_t)b * 9 * HW;
    _Float16* khb = kh + (size_t)b * 9 * HW;
    float v0[9], v1[9];
    float s0 = 0.f, s1 = 0.f;
#pragma unroll
    for (int c = 0; c < 9; ++c) {
        float2 fv = *(const float2*)(fb + (size_t)c * HW + base);
        v0[c] = fv.x; v1[c] = fv.y;
        s0 += fabsf(fv.x); s1 += fabsf(fv.y);
    }
    float r0 = 1.f / fmaxf(s0, EPSF);
    float r1 = 1.f / fmaxf(s1, EPSF);
#pragma unroll
    for (int c = 0; c < 9; ++c) {
        khb[(size_t)c * HW + base]     = (_Float16)(v0[c] * r0);
        khb[(size_t)c * HW + base + 1] = (_Float16)(v1[c] * r1);
    }
}

// ---------- K1: role-split  (z0: beta/d-build + K^TK ; z1: L^TL) ----------
// KH=1: z1 uses precomputed fp16 kern.  KH=0: round-6 fp32 fallback.

template <int KH>
__global__ __launch_bounds__(256, 4) void K1(
    const float* __restrict__ r, const float* __restrict__ dold, float* __restrict__ dnew,
    float* __restrict__ qa, float* __restrict__ qb,
    const float* __restrict__ f, const _Float16* __restrict__ kern,
    const float* __restrict__ kk,
    const float* __restrict__ rrp, float* __restrict__ dqa, float* __restrict__ dqb,
    const float* __restrict__ deltaO, float* __restrict__ deltaN,
    const int* __restrict__ convO, int* __restrict__ convN,
    float* __restrict__ thrS, int isFirst)
{
    __shared__ SMemU sm;
    __shared__ float red[256];
    __shared__ float krs[25];

    int id = blockIdx.x;
    int b = id & 7;
    int bxg = id >> 3;
    int tid = threadIdx.x;
    bool roleK = (bxg < NZ0);
    size_t bHW = (size_t)b * HW;
    const float* rb = r + bHW;
    const float* db = dold + bHW;

    // ---- batched preload (issued before the reduce for latency overlap) ----
    float rv[8], dv[8];
    float freg[3][9];
    int r0, c0;
    if (roleK) {
        int ty = bxg / 12, tx = bxg - ty * 12;
        r0 = ty * 32; c0 = tx * 32;
        if (tid < 25) krs[tid] = kk[b * 25 + tid];
#pragma unroll
        for (int p = 0; p < 8; ++p) {
            int e = p * 256 + tid;
            int a = e / 44, ee = e - a * 44;
            int gr = r0 - 6 + a, gc = c0 - 6 + ee;
            bool v = (e < 1936) && ((unsigned)gr < (unsigned)Hdim) && ((unsigned)gc < (unsigned)Wdim);
            size_t gg = (size_t)gr * Wdim + gc;
            rv[p] = v ? rb[gg] : 0.f;
            dv[p] = (v && !isFirst) ? db[gg] : 0.f;
        }
    } else {
        int bxl = bxg - NZ0;
        int ty = bxl / 12, tx = bxl - ty * 12;
        r0 = ty * 16; c0 = tx * 32;
#pragma unroll
        for (int p = 0; p < 3; ++p) {
            int e = p * 256 + tid;
            int a = e / 34, ee = e - a * 34;
            int gr = r0 - 1 + a, gc = c0 - 1 + ee;
            bool v = (e < 612) && ((unsigned)gr < (unsigned)Hdim) && ((unsigned)gc < (unsigned)Wdim);
            size_t gg = (size_t)gr * Wdim + gc;
            if (KH) {
                const _Float16* khb = kern + (size_t)b * 9 * HW;
#pragma unroll
                for (int c = 0; c < 9; ++c)
                    freg[p][c] = v ? (float)khb[(size_t)c * HW + gg] : 0.f;
            } else {
                const float* fb = f + (size_t)b * 9 * HW;
#pragma unroll
                for (int c = 0; c < 9; ++c)
                    freg[p][c] = v ? fb[(size_t)c * HW + gg] : 0.f;
            }
        }
#pragma unroll
        for (int p = 0; p < 3; ++p) {
            int e = p * 256 + tid;
            int a = e / 36, ee = e - a * 36;
            int gr = r0 - 2 + a, gc = c0 - 2 + ee;
            bool v = (e < 720) && ((unsigned)gr < (unsigned)Hdim) && ((unsigned)gc < (unsigned)Wdim);
            size_t gg = (size_t)gr * Wdim + gc;
            rv[p] = v ? rb[gg] : 0.f;
            dv[p] = (v && !isFirst) ? db[gg] : 0.f;
        }
    }

    // ---- beta reduce (identical tree in every block -> identical bits) ----
    float s = rrp[b * NPB + tid] + ((tid < 32) ? rrp[b * NPB + 256 + tid] : 0.f);
    red[tid] = s; __syncthreads();
    for (int st = 128; st > 0; st >>= 1) {
        if (tid < st) red[tid] += red[tid + st];
        __syncthreads();
    }
    float delta = red[0];
    __syncthreads();
    float beta = isFirst ? 0.f : delta / deltaO[b];
    if (bxg == 0 && tid == 0) {
        deltaN[b] = delta;
        if (isFirst) {
            float th = TOLF * delta;
            thrS[b] = th;
            convN[b] = (delta <= th) ? 1 : 0;
        } else {
            convN[b] = (convO[b] || delta <= thrS[b]) ? 1 : 0;
        }
    }

    if (roleK) {
        // ---- z0: ds = d_new over tile+halo6 from regs ----
#pragma unroll
        for (int p = 0; p < 8; ++p) {
            int e = p * 256 + tid;
            if (e < 1936) {
                int a = e / 44, ee = e - a * 44;
                sm.z0.ds[a][ee] = isFirst ? rv[p] : rv[p] + beta * dv[p];
            }
        }
        __syncthreads();

        int trr = tid >> 3, tcc = (tid & 7) << 2;
        size_t ooff = bHW + (size_t)(r0 + trr) * Wdim + c0 + tcc;
        float4 dn4 = make_float4(sm.z0.ds[trr + 6][tcc + 6], sm.z0.ds[trr + 6][tcc + 7],
                                 sm.z0.ds[trr + 6][tcc + 8], sm.z0.ds[trr + 6][tcc + 9]);
        *(float4*)(dnew + ooff) = dn4;

        bool interior = (r0 >= 32 && r0 <= 320 && c0 >= 32 && c0 <= 320);

        // ---- t1 = sym_conv(d) over tile + halo 4 ----
        if (interior) {
            for (int e = tid; e < 400; e += 256) {
                int lr = e / 10, lc4 = (e - lr * 10) * 4;
                float a0 = 0, a1 = 0, a2 = 0, a3 = 0;
#pragma unroll
                for (int u = 0; u < 5; ++u) {
                    const float* drow = &sm.z0.ds[lr + 4 - u][lc4];
                    float w[8];
#pragma unroll
                    for (int z = 0; z < 8; ++z) w[z] = drow[z];
#pragma unroll
                    for (int v = 0; v < 5; ++v) {
                        float kv = krs[u * 5 + v];
                        a0 += kv * w[4 - v]; a1 += kv * w[5 - v];
                        a2 += kv * w[6 - v]; a3 += kv * w[7 - v];
                    }
                }
                sm.z0.t1s[lr][lc4] = a0; sm.z0.t1s[lr][lc4 + 1] = a1;
                sm.z0.t1s[lr][lc4 + 2] = a2; sm.z0.t1s[lr][lc4 + 3] = a3;
            }
        } else {
            for (int e = tid; e < T1H * T1W; e += 256) {
                int lr = e / T1W, lc = e - lr * T1W;
                int gi = r0 - 4 + lr, gj = c0 - 4 + lc;
                float v = 0.f;
                if ((unsigned)gi < (unsigned)Hdim && (unsigned)gj < (unsigned)Wdim) {
                    float acc = 0.f;
#pragma unroll
                    for (int u = 0; u < 5; ++u) {
                        int rr = symidx(gi + 2 - u, Hdim) - (r0 - 6);
#pragma unroll
                        for (int vv = 0; vv < 5; ++vv) {
                            int cc = symidx(gj + 2 - vv, Wdim) - (c0 - 6);
                            acc += krs[u * 5 + vv] * sm.z0.ds[rr][cc];
                        }
                    }
                    v = acc;
                }
                sm.z0.t1s[lr][lc] = v;
            }
        }
        __syncthreads();

        // ---- qa = sym_conv_T(t1) ; dq_a partials ----
        int m = r0 + trr, n = c0 + tcc;
        float q0, q1, q2, q3;
        if (interior) {
            float a0 = 0, a1 = 0, a2 = 0, a3 = 0;
#pragma unroll
            for (int u = 0; u < 5; ++u) {
                const float* t1row = &sm.z0.t1s[trr + 2 + u][tcc + 2];
                float w[8];
#pragma unroll
                for (int z = 0; z < 8; ++z) w[z] = t1row[z];
#pragma unroll
                for (int v = 0; v < 5; ++v) {
                    float kv = krs[u * 5 + v];
                    a0 += kv * w[v]; a1 += kv * w[v + 1];
                    a2 += kv * w[v + 2]; a3 += kv * w[v + 3];
                }
            }
            q0 = a0; q1 = a1; q2 = a2; q3 = a3;
        } else {
            float qo[4];
#pragma unroll
            for (int o = 0; o < 4; ++o) {
                int nn = n + o;
                int pr[2]; int nr = 0;
                pr[nr++] = m + 2;
                if (m < 2)         pr[nr++] = 1 - m;
                if (m >= Hdim - 2) pr[nr++] = 2 * Hdim + 1 - m;
                int pc[2]; int nc = 0;
                pc[nc++] = nn + 2;
                if (nn < 2)         pc[nc++] = 1 - nn;
                if (nn >= Wdim - 2) pc[nc++] = 2 * Wdim + 1 - nn;
                float acc = 0.f;
                for (int a = 0; a < nr; ++a) {
                    int p = pr[a];
                    for (int bb = 0; bb < nc; ++bb) {
                        int qq2 = pc[bb];
#pragma unroll
                        for (int u = 0; u < 5; ++u) {
                            int rr = p + u - 4;
                            if ((unsigned)rr < (unsigned)Hdim) {
                                int lrr = rr - (r0 - 4);
#pragma unroll
                                for (int v = 0; v < 5; ++v) {
                                    int cc = qq2 + v - 4;
                                    if ((unsigned)cc < (unsigned)Wdim)
                                        acc += krs[u * 5 + v] * sm.z0.t1s[lrr][cc - (c0 - 4)];
                                }
                            }
                        }
                    }
                }
                qo[o] = acc;
            }
            q0 = qo[0]; q1 = qo[1]; q2 = qo[2]; q3 = qo[3];
        }
        *(float4*)(qa + ooff) = make_float4(q0, q1, q2, q3);

        float pdq = dn4.x * q0 + dn4.y * q1 + dn4.z * q2 + dn4.w * q3;
        red[tid] = pdq; __syncthreads();
        for (int st = 128; st > 0; st >>= 1) {
            if (tid < st) red[tid] += red[tid + st];
            __syncthreads();
        }
        if (tid == 0) dqa[b * NZ0 + bxg] = red[0];

    } else {
        int bxl = bxg - NZ0;
        // qs zero-init + dsm fill from regs
        for (int e = tid; e < 16 * 33; e += 256) ((float*)sm.z1.qs)[e] = 0.f;
#pragma unroll
        for (int p = 0; p < 3; ++p) {
            int e = p * 256 + tid;
            if (e < 720) {
                int a = e / 36, ee = e - a * 36;
                sm.z1.dsm[a][ee] = isFirst ? rv[p] : rv[p] + beta * dv[p];
            }
        }
        __syncthreads();

        // u2 at 18x34 source slots
        float u2r[3];
#pragma unroll
        for (int p = 0; p < 3; ++p) {
            int e = p * 256 + tid;
            float uv = 0.f;
            if (e < 612) {
                int sa = e / 34, se = e - sa * 34;
                if (KH) {
                    float acc = 0.f;
#pragma unroll
                    for (int c = 0; c < 9; ++c)
                        acc += freg[p][c] * sm.z1.dsm[sa + c / 3][se + c % 3];
                    uv = acc;      // kern already normalized
                } else {
                    float acc = 0.f, sab = 0.f;
#pragma unroll
                    for (int c = 0; c < 9; ++c) {
                        acc += freg[p][c] * sm.z1.dsm[sa + c / 3][se + c % 3];
                        sab += fabsf(freg[p][c]);
                    }
                    float rd = 1.f / fmaxf(sab, EPSF);
                    uv = rd * rd * acc;
                }
            }
            u2r[p] = uv;
        }
        __syncthreads();

        // scatter adjoint KPN into qs (9 race-free rounds)
#pragma unroll
        for (int c = 0; c < 9; ++c) {
            int di = c / 3, dj = c % 3;
#pragma unroll
            for (int p = 0; p < 3; ++p) {
                int e = p * 256 + tid;
                if (e < 612) {
                    int sa = e / 34, se = e - sa * 34;
                    int tr = sa + di - 2, tc = se + dj - 2;
                    if ((unsigned)tr < 16u && (unsigned)tc < 32u)
                        sm.z1.qs[tr][tc] += freg[p][c] * u2r[p];
                }
            }
            __syncthreads();
        }

        int trr = tid >> 4, tcc = (tid & 15) << 1;
        size_t ooff = bHW + (size_t)(r0 + trr) * Wdim + c0 + tcc;
        float q0 = sm.z1.qs[trr][tcc], q1 = sm.z1.qs[trr][tcc + 1];
        *(float2*)(qb + ooff) = make_float2(q0, q1);
        float d0 = sm.z1.dsm[trr + 2][tcc + 2], d1 = sm.z1.dsm[trr + 2][tcc + 3];
        float pdq = d0 * q0 + d1 * q1;
        red[tid] = pdq; __syncthreads();
        for (int st = 128; st > 0; st >>= 1) {
            if (tid < st) red[tid] += red[tid + st];
            __syncthreads();
        }
        if (tid == 0) dqb[b * NZ1 + bxl] = red[0];
    }
}

// ---------- K2: alpha ; q=qa+lam*qb ; x += a d ; r -= a q ; rr partials ----------

__global__ __launch_bounds__(256) void K2(
    const float* __restrict__ dqa, const float* __restrict__ dqb, const float* __restrict__ rw,
    const float* __restrict__ deltaN, const int* __restrict__ convN,
    const float* __restrict__ d, const float* __restrict__ qa, const float* __restrict__ qb,
    float* __restrict__ x, float* __restrict__ r, float* __restrict__ rrp)
{
    __shared__ float red[512];
    int id = blockIdx.x;
    int b = id & 7, bx = id >> 3, tid = threadIdx.x;
    float sA = (tid < NZ0) ? dqa[b * NZ0 + tid] : 0.f;
    float sB = dqb[b * NZ1 + tid] + ((tid < 32) ? dqb[b * NZ1 + 256 + tid] : 0.f);
    red[tid] = sA; red[256 + tid] = sB;
    __syncthreads();
    for (int st = 128; st > 0; st >>= 1) {
        if (tid < st) { red[tid] += red[tid + st]; red[256 + tid] += red[256 + tid + st]; }
        __syncthreads();
    }
    float lam = expf(rw[0]);
    float dq = red[0] + lam * red[256];
    float a = convN[b] ? 0.f : deltaN[b] / dq;
    __syncthreads();

    size_t off = (size_t)b * HW + ((size_t)bx * 256 + tid) * 2;
    float2 d2  = *(const float2*)(d + off);
    float2 qa2 = *(const float2*)(qa + off);
    float2 qb2 = *(const float2*)(qb + off);
    float2 xv  = *(float2*)(x + off);
    float2 rv  = *(float2*)(r + off);
    float q0 = qa2.x + lam * qb2.x, q1 = qa2.y + lam * qb2.y;
    xv.x += a * d2.x; xv.y += a * d2.y;
    rv.x -= a * q0;   rv.y -= a * q1;
    *(float2*)(x + off) = xv;
    *(float2*)(r + off) = rv;

    float ps = rv.x * rv.x + rv.y * rv.y;
    red[tid] = ps; __syncthreads();
    for (int st = 128; st > 0; st >>= 1) {
        if (tid < st) red[tid] += red[tid + st];
        __syncthreads();
    }
    if (tid == 0) rrp[b * NPB + bx] = red[0];
}

// ---------- launch ----------

extern "C" void kernel_launch(void* const* d_in, const int* in_sizes, int n_in,
                              void* d_out, int out_size, void* d_ws, size_t ws_size,
                              hipStream_t stream) {
    const float* y  = (const float*)d_in[0];   // [8,1,384,384]
    const float* kk = (const float*)d_in[1];   // [8,5,5]
    const float* f  = (const float*)d_in[2];   // [8,9,384,384]
    const float* rw = (const float*)d_in[3];   // [1]

    float* x = (float*)d_out;
    float* ws = (float*)d_ws;
    const size_t N = (size_t)Bn * HW;

    float* r   = ws;
    float* d0  = ws + 1 * N;
    float* d1  = ws + 2 * N;
    float* qa  = ws + 3 * N;
    float* qb  = ws + 4 * N;
    float* P   = ws + 5 * N;
    float* dqa = P;                       P += (size_t)Bn * NZ0;
    float* dqb = P;                       P += (size_t)Bn * NZ1;
    float* rrp = P;                       P += (size_t)Bn * NPB;
    float* delta = P;                     P += 2 * Bn;
    float* thr   = P;                     P += Bn;
    int*   conv  = (int*)P;               P += 2 * Bn;
    _Float16* kern = (_Float16*)P;        // 9N halves
    size_t needBytes = ((size_t)(P - ws)) * 4 + 9 * N * 2;
    int useH = (ws_size >= needBytes) ? 1 : 0;
    float* db[2] = { d0, d1 };

    dim3 blk(256);

    k_init<<<dim3(NPB, Bn), blk, 0, stream>>>(y, kk, r, x, rrp);
    if (useH) k_prep<<<dim3(NPB * Bn), blk, 0, stream>>>(f, kern);

    for (int t = 0; t < MAXITER; ++t) {
        int i = t & 1, o = i ^ 1;
        if (useH) {
            K1<1><<<dim3((NZ0 + NZ1) * Bn), blk, 0, stream>>>(
                r, db[i], db[o], qa, qb, f, kern, kk,
                rrp, dqa, dqb,
                delta + i * Bn, delta + o * Bn,
                conv + i * Bn, conv + o * Bn,
                thr, t == 0 ? 1 : 0);
        } else {
            K1<0><<<dim3((NZ0 + NZ1) * Bn), blk, 0, stream>>>(
                r, db[i], db[o], qa, qb, f, kern, kk,
                rrp, dqa, dqb,
                delta + i * Bn, delta + o * Bn,
                conv + i * Bn, conv + o * Bn,
                thr, t == 0 ? 1 : 0);
        }
        K2<<<dim3(NPB * Bn), blk, 0, stream>>>(
            dqa, dqb, rw, delta + o * Bn, conv + o * Bn,
            db[o], qa, qb, x, r, rrp);
    }
}